// Round 4
// baseline (261.391 us; speedup 1.0000x reference)
//
#include <hip/hip_runtime.h>
#include <hip/hip_bf16.h>
#include <stdint.h>

#define N_REP 8
#define BATCH 32
#define NIN   128
#define NOUT  128
#define EDIM  1024
#define MDIM  130
#define ETILE 128
#define SE    130   // LDS row stride in dwords (mp rows)
#define TILES 4

typedef __attribute__((ext_vector_type(8))) short short8;
typedef __attribute__((ext_vector_type(4))) float f32x4;

__device__ __forceinline__ unsigned short f2bf(float f) {
    union { float f; uint32_t u; } v;
    v.f = f;
    uint32_t u = v.u;
    uint32_t r = u + 0x7fffu + ((u >> 16) & 1u);   // RNE
    return (unsigned short)(r >> 16);
}

__device__ __forceinline__ uint32_t pk2bf(float lo, float hi) {
    __hip_bfloat162 h = __float22bfloat162_rn(make_float2(lo, hi)); // .x -> low16
    uint32_t d;
    __builtin_memcpy(&d, &h, 4);
    return d;
}

// One wave per (n,o). Emits S[n][o][m] = W*sign (bf16, K-minor) and bias[n][o].
__global__ __launch_bounds__(64)
void prep_kernel(const float* __restrict__ theta,
                 const float* __restrict__ noise,
                 unsigned short* __restrict__ Sg,
                 float* __restrict__ biasg) {
    const int n = blockIdx.x >> 7;
    const int o = blockIdx.x & 127;
    const int lane = threadIdx.x;

    const float* nb = noise + (size_t)n * MDIM * NOUT + o;
    auto tn_at = [&](int m) -> float {
        float t = theta[m * NOUT + o];
        t = fminf(fmaxf(t, -1.f), 1.f);
        if (fabsf(t) < 0.01f) t = 0.f;
        return t * fmaf(nb[m * NOUT], 0.2f, 0.9f);
    };

    const float t0 = tn_at(lane);
    const float t1 = tn_at(lane + 64);
    const float t2 = (lane < 2) ? tn_at(128 + lane) : 0.f;

    float s = fabsf(t0) + fabsf(t1) + fabsf(t2);
#pragma unroll
    for (int d = 1; d < 64; d <<= 1) s += __shfl_xor(s, d, 64);
    const float inv = 1.f / (s + 1e-10f);

    const float w0 = fabsf(t0) * inv, w1 = fabsf(t1) * inv;
    unsigned short* srow = Sg + ((size_t)n * NOUT + o) * NIN;
    srow[lane]      = f2bf(t0 >= 0.f ? w0 : -w0);
    srow[lane + 64] = f2bf(t1 >= 0.f ? w1 : -w1);

    float b = (t0 < 0.f ? w0 : 0.f) + (t1 < 0.f ? w1 : 0.f);
    if (lane == 0 && t2 >= 0.f) b += fabsf(t2) * inv;   // ones-column positive part
#pragma unroll
    for (int d = 1; d < 64; d <<= 1) b += __shfl_xor(b, d, 64);
    if (lane == 0) biasg[n * NOUT + o] = b;
}

// Persistent pipelined GEMM: 512 blocks (2/CU), each does 4 e-tiles for one (n,b)
// with double-buffered LDS. D[e][o] orientation -> dwordx4 epilogue stores.
__global__ __launch_bounds__(256, 2)
void gemm_kernel(const float* __restrict__ a,
                 const unsigned short* __restrict__ Sg,
                 const float* __restrict__ biasg,
                 const float* __restrict__ eta,
                 float* __restrict__ out) {
    __shared__ uint32_t Alds[2][64 * SE];            // 2 x 33280 B
    const int bid = blockIdx.x;
    const int nb  = bid >> 1;                        // n*B + b
    const int eh  = bid & 1;                         // e-half: tiles eh*4 .. eh*4+3
    const int n   = nb >> 5;
    const int tid = threadIdx.x;
    const int lane = tid & 63;
    const int w = tid >> 6;                          // 2x2 waves over (o,e)
    const int r = lane & 15;
    const int q = lane >> 4;
    const int o_base = (w & 1) << 6;
    const int e_base = (w >> 1) << 6;

    // ---- per-block persistent state: S frags (B-operand), bias, eta ----
    short8 sf[4][4];                                 // [ks][fo]
#pragma unroll
    for (int ks = 0; ks < 4; ++ks)
#pragma unroll
        for (int fo = 0; fo < 4; ++fo) {
            const int o = o_base + (fo << 4) + r;
            sf[ks][fo] = *(const short8*)(Sg + ((size_t)(n * NOUT + o) << 7) + (ks << 5) + (q << 3));
        }
    float bv[4];
#pragma unroll
    for (int fo = 0; fo < 4; ++fo)
        bv[fo] = biasg[n * NOUT + o_base + (fo << 4) + r];
    // out = (e0+e1) - 2*e1 / (exp2((z-e2)*2*e3*log2e) + 1)
    const float kk = eta[3] * 2.885390082f;          // 2*e3*log2(e)
    const float kd = -eta[2] * kk;
    const float kA = eta[0] + eta[1];
    const float kB = 2.f * eta[1];

    const float* abase0 = a   + (size_t)nb * (NIN  * EDIM) + (size_t)(eh << 2) * ETILE;
    float*       obase0 = out + (size_t)nb * (NOUT * EDIM) + (size_t)(eh << 2) * ETILE;

    const int e4  = (tid & 31) << 2;                 // 0..124
    const int mp0 = tid >> 5;                        // 0..7

    float4 pf[8];
    auto issue = [&](int t, int half) {              // 8 float4 loads of tile t
        const float* ab = abase0 + t * ETILE;
#pragma unroll
        for (int it = 0; it < 4; ++it) {
            const int mp = mp0 + (it << 3) + (half << 5);
            pf[2 * it]     = *(const float4*)(ab + (size_t)(2 * mp)     * EDIM + e4);
            pf[2 * it + 1] = *(const float4*)(ab + (size_t)(2 * mp + 1) * EDIM + e4);
        }
    };
    auto commit = [&](int buf, int half) {           // cvt + ds_write packed m-pairs
#pragma unroll
        for (int it = 0; it < 4; ++it) {
            const int mp = mp0 + (it << 3) + (half << 5);
            uint2 d0, d1;
            d0.x = pk2bf(pf[2 * it].x, pf[2 * it + 1].x);
            d0.y = pk2bf(pf[2 * it].y, pf[2 * it + 1].y);
            d1.x = pk2bf(pf[2 * it].z, pf[2 * it + 1].z);
            d1.y = pk2bf(pf[2 * it].w, pf[2 * it + 1].w);
            *(uint2*)&Alds[buf][mp * SE + e4]     = d0;
            *(uint2*)&Alds[buf][mp * SE + e4 + 2] = d1;
        }
    };

    // ---- prologue: stage tile 0 into buffer 0 ----
    issue(0, 0); commit(0, 0);
    issue(0, 1); commit(0, 1);
    __syncthreads();

    for (int t = 0; t < TILES; ++t) {
        const int cur = t & 1;

        if (t < TILES - 1) issue(t + 1, 0);          // prefetch half 0

        f32x4 acc[4][4];                             // [fe][fo]
#pragma unroll
        for (int fe = 0; fe < 4; ++fe)
#pragma unroll
            for (int fo = 0; fo < 4; ++fo)
                acc[fe][fo] = (f32x4){0.f, 0.f, 0.f, 0.f};

#pragma unroll
        for (int ks = 0; ks < 4; ++ks) {
            if (ks == 2 && t < TILES - 1) {          // mid-loop: drain half0, prefetch half1
                commit(cur ^ 1, 0);
                issue(t + 1, 1);
            }
            short8 af[4];
            const int mpb = (ks << 4) + (q << 2);
#pragma unroll
            for (int fe = 0; fe < 4; ++fe) {
                const int e = e_base + (fe << 4) + r;
                uint32_t d[4];
#pragma unroll
                for (int jj = 0; jj < 4; ++jj)
                    d[jj] = Alds[cur][(mpb + jj) * SE + e];
                __builtin_memcpy(&af[fe], d, 16);
            }
#pragma unroll
            for (int fe = 0; fe < 4; ++fe)
#pragma unroll
                for (int fo = 0; fo < 4; ++fo)
                    acc[fe][fo] = __builtin_amdgcn_mfma_f32_16x16x32_bf16(
                        af[fe], sf[ks][fo], acc[fe][fo], 0, 0, 0);
        }

        if (t < TILES - 1) {
            commit(cur ^ 1, 1);
            __syncthreads();
        }

        // ---- epilogue tile t: D[e][o] -> row = e = q*4+i, col = o = r ----
        float* obase = obase0 + t * ETILE;
#pragma unroll
        for (int fo = 0; fo < 4; ++fo) {
            const int o = o_base + (fo << 4) + r;
            float* orow = obase + (size_t)o * EDIM;
#pragma unroll
            for (int fe = 0; fe < 4; ++fe) {
                float vv[4];
#pragma unroll
                for (int i = 0; i < 4; ++i) {
                    const float z  = acc[fe][fo][i] + bv[fo];
                    const float ex = __builtin_amdgcn_exp2f(fmaf(z, kk, kd));
                    vv[i] = fmaf(-kB, __builtin_amdgcn_rcpf(ex + 1.f), kA);
                }
                *(float4*)(orow + e_base + (fe << 4) + (q << 2)) = *(float4*)vv;
            }
        }
    }
}

extern "C" void kernel_launch(void* const* d_in, const int* in_sizes, int n_in,
                              void* d_out, int out_size, void* d_ws, size_t ws_size,
                              hipStream_t stream) {
    const float* a     = (const float*)d_in[0];
    const float* theta = (const float*)d_in[1];
    const float* noise = (const float*)d_in[2];
    const float* eta   = (const float*)d_in[3];
    float* out = (float*)d_out;

    unsigned short* Sg = (unsigned short*)d_ws;      // 8*128*128 bf16 = 256 KiB
    float* biasg = (float*)((char*)d_ws + (size_t)N_REP * NOUT * NIN * sizeof(unsigned short));

    prep_kernel<<<N_REP * NOUT, 64, 0, stream>>>(theta, noise, Sg, biasg);
    gemm_kernel<<<N_REP * BATCH * 2, 256, 0, stream>>>(a, Sg, biasg, eta, out);
}